// Round 9
// baseline (394.682 us; speedup 1.0000x reference)
//
#include <hip/hip_runtime.h>
#include <hip/hip_fp16.h>
#include <math.h>

// R26: replace the zero-atomic bucket CSR build (hist+scan+scatter+LDS-sort,
// ~45MB traffic, two edge-data round trips) with a direct global-atomic build:
// zero(deg) -> deg(atomicAdd) -> scanA(reduce+ticket) -> scanB(local scan +
// rowstart/cur/dis/xd) -> scatter_direct(pos=atomicAdd(cur[c]); csr_src[pos]=r).
// Device-scope atomics over 100K addresses (avg 16/addr) are cheap on gfx950
// (G12/m20); eliminates counts+storage+csr_build entirely (~31MB traffic).
// Layers unchanged from R25 (gather16). csr_src intra-node order becomes
// race-ordered: fp32 sum jitter ~1e-6 << fp16-dominated absmax 4.9e-4.
// History: R18 228.9 | R21 228.1 | R22 757.5 | R23 244.8 | R24b 424.0 | R25 227.5.

#define N_NODES 100000
#define F 32
#define NSCB ((N_NODES + 1023) / 1024)          // 98 scan blocks

// ---------------- zero deg + re-arm ticket ----------------
__global__ void zero_kernel(int* __restrict__ deg, int* __restrict__ ticket) {
    int i = blockIdx.x * 1024 + threadIdx.x;
    if (i < N_NODES) deg[i] = 0;
    if (i == 0) *ticket = 0;
}

// ---------------- pass 1: degree count (fire-and-forget atomics) ----------------
__global__ void deg_kernel(const int* __restrict__ col, int* __restrict__ deg, int E) {
    int pairs = E >> 1;
    const int2* c2 = (const int2*)col;           // col 8B-aligned when E even
    int stride = gridDim.x * blockDim.x;
    for (int p = blockIdx.x * blockDim.x + threadIdx.x; p < pairs; p += stride) {
        int2 c = c2[p];
        atomicAdd(&deg[c.x], 1);
        atomicAdd(&deg[c.y], 1);
    }
    if ((E & 1) && blockIdx.x == 0 && threadIdx.x == 0) atomicAdd(&deg[col[E - 1]], 1);
}

// ---------------- pass 2a: per-block totals + ticket last-block serial scan ----------------
__global__ void scanA_kernel(const int* __restrict__ deg, int* __restrict__ blockoff,
                             int* __restrict__ rowstart, int* __restrict__ ticket) {
    __shared__ int red[1024];
    int tid = threadIdx.x, blk = blockIdx.x;
    int i = blk * 1024 + tid;
    red[tid] = (i < N_NODES) ? deg[i] : 0;
    __syncthreads();
    for (int st = 512; st > 0; st >>= 1) {
        if (tid < st) red[tid] += red[tid + st];
        __syncthreads();
    }
    if (tid == 0) blockoff[blk] = red[0];
    // ---- decoupled last block: exclusive scan of the 98 partials ----
    __shared__ int lastflag;
    __threadfence();
    __syncthreads();
    if (tid == 0) lastflag = (atomicAdd(ticket, 1) == (int)gridDim.x - 1);
    __syncthreads();
    if (!lastflag) return;
    __threadfence();
    if (tid == 0) {
        int running = 0;
        for (int b = 0; b < NSCB; b++) {
            int t = blockoff[b];
            blockoff[b] = running;
            running += t;
        }
        rowstart[N_NODES] = running;             // == E
    }
}

// ---------------- pass 2b: block-local scan -> rowstart/cur + dis + xd ----------------
__global__ void scanB_kernel(const int* __restrict__ deg, const int* __restrict__ blockoff,
                             int* __restrict__ rowstart, int* __restrict__ cur,
                             float* __restrict__ dis, const float* __restrict__ x,
                             float* __restrict__ xd) {
    __shared__ int psum[1024];
    int tid = threadIdx.x, blk = blockIdx.x;
    int i = blk * 1024 + tid;
    int d = (i < N_NODES) ? deg[i] : 0;
    psum[tid] = d;
    __syncthreads();
    for (int off = 1; off < 1024; off <<= 1) {
        int v = (tid >= off) ? psum[tid - off] : 0;
        __syncthreads();
        psum[tid] += v;
        __syncthreads();
    }
    if (i < N_NODES) {
        int pos = blockoff[blk] + psum[tid] - d;     // exclusive prefix
        rowstart[i] = pos;
        cur[i] = pos;
        float dv = (d > 0) ? rsqrtf((float)d) : 0.0f;
        dis[i] = dv;
        float x0 = x[(size_t)i * 5 + 0], x1 = x[(size_t)i * 5 + 1], x2 = x[(size_t)i * 5 + 2];
        float x3 = x[(size_t)i * 5 + 3], x4 = x[(size_t)i * 5 + 4];
        float* xo = xd + (size_t)i * 8;
        xo[0] = dv * x0; xo[1] = dv * x1; xo[2] = dv * x2; xo[3] = dv * x3;
        xo[4] = dv * x4; xo[5] = 0.0f;   xo[6] = 0.0f;   xo[7] = 0.0f;
    }
}

// ---------------- pass 3: direct scatter via atomic cursors ----------------
__global__ void scatter_direct(const int* __restrict__ row, const int* __restrict__ col,
                               int* __restrict__ cur, int* __restrict__ csr_src, int E) {
    int pairs = E >> 1;
    const int2* c2 = (const int2*)col;
    const int2* r2 = (const int2*)row;
    int stride = gridDim.x * blockDim.x;
    for (int p = blockIdx.x * blockDim.x + threadIdx.x; p < pairs; p += stride) {
        int2 c = c2[p];
        int2 r = r2[p];
        int pos0 = atomicAdd(&cur[c.x], 1);
        csr_src[pos0] = r.x;
        int pos1 = atomicAdd(&cur[c.y], 1);
        csr_src[pos1] = r.y;
    }
    if ((E & 1) && blockIdx.x == 0 && threadIdx.x == 0) {
        int c = col[E - 1], r = row[E - 1];
        int pos = atomicAdd(&cur[c], 1);
        csr_src[pos] = r;
    }
}

// ---------------- layer 1 fused: gather xd (8 lanes/node) + W1 transform -> gd_a fp16 ----------------
__global__ void layer1_fused(const float* __restrict__ xd, const int* __restrict__ rowstart,
                             const int* __restrict__ csr_src, const float* __restrict__ dis,
                             const float* __restrict__ W1, const float* __restrict__ b1,
                             __half* __restrict__ gda, int n) {
    __shared__ float Ws[5 * F];
    __shared__ float s1s[32][8];
    int tid = threadIdx.x;
    if (tid < 5 * F) Ws[tid] = W1[tid];
    int grp = tid >> 3, f = tid & 7;
    int node = blockIdx.x * 32 + grp;
    float sum = 0.0f;
    if (node < n) {
        int start = rowstart[node], end = rowstart[node + 1];
        float a0 = 0, a1 = 0, a2 = 0, a3 = 0, a4 = 0, a5 = 0, a6 = 0, a7 = 0;
        int i = start;
        for (; i + 7 < end; i += 8) {
            int r0 = csr_src[i], r1 = csr_src[i+1], r2 = csr_src[i+2], r3 = csr_src[i+3];
            int r4 = csr_src[i+4], r5 = csr_src[i+5], r6 = csr_src[i+6], r7 = csr_src[i+7];
            a0 += xd[r0*8+f]; a1 += xd[r1*8+f]; a2 += xd[r2*8+f]; a3 += xd[r3*8+f];
            a4 += xd[r4*8+f]; a5 += xd[r5*8+f]; a6 += xd[r6*8+f]; a7 += xd[r7*8+f];
        }
        for (; i < end; i++) a0 += xd[csr_src[i]*8+f];
        sum = ((a0+a1)+(a2+a3)) + ((a4+a5)+(a6+a7));
    }
    s1s[grp][f] = sum;
    __syncthreads();
    if (node < n) {
        float dv = dis[node];
        float sk0 = dv * s1s[grp][0], sk1 = dv * s1s[grp][1], sk2 = dv * s1s[grp][2];
        float sk3 = dv * s1s[grp][3], sk4 = dv * s1s[grp][4];
        int fb = f * 4;
#pragma unroll
        for (int j = 0; j < 4; j++) {
            int ff = fb + j;
            float acc = b1[ff] + sk0 * Ws[0*F+ff] + sk1 * Ws[1*F+ff] + sk2 * Ws[2*F+ff]
                       + sk3 * Ws[3*F+ff] + sk4 * Ws[4*F+ff];
            float h = acc > 0.0f ? acc : 0.0f;
            gda[(size_t)node * F + ff] = __float2half(dv * h);
        }
    }
}

// ======== 16-deep 8-lane gather: 16 edges in flight, next-16 indices prefetched ========
__device__ __forceinline__ void gather16(const uint2* __restrict__ gin2,
                                         const int* __restrict__ csr_src,
                                         int start, int end, int l,
                                         float& a0, float& a1, float& a2, float& a3) {
    a0 = a1 = a2 = a3 = 0.0f;
    int i = start;
    if (i + 16 <= end) {
        int i0 = csr_src[i + l];
        int i1 = csr_src[i + 8 + l];
        while (i + 16 <= end) {
            int nexti = i + 16;
            int n0 = 0, n1 = 0;
            if (nexti + 16 <= end) {
                n0 = csr_src[nexti + l];
                n1 = csr_src[nexti + 8 + l];
            }
            uint2 v[16];
#pragma unroll
            for (int j = 0; j < 8; j++) {
                int r = __shfl(i0, j, 8);
                v[j] = gin2[(size_t)r * 8 + l];
            }
#pragma unroll
            for (int j = 0; j < 8; j++) {
                int r = __shfl(i1, j, 8);
                v[8 + j] = gin2[(size_t)r * 8 + l];
            }
#pragma unroll
            for (int j = 0; j < 16; j++) {
                float2 f0 = __half22float2(*(__half2*)&v[j].x);
                float2 f1 = __half22float2(*(__half2*)&v[j].y);
                a0 += f0.x; a1 += f0.y; a2 += f1.x; a3 += f1.y;
            }
            i0 = n0; i1 = n1;
            i = nexti;
        }
    }
    if (i + 8 <= end) {
        int idx = csr_src[i + l];
        uint2 v[8];
#pragma unroll
        for (int j = 0; j < 8; j++) {
            int r = __shfl(idx, j, 8);
            v[j] = gin2[(size_t)r * 8 + l];
        }
#pragma unroll
        for (int j = 0; j < 8; j++) {
            float2 f0 = __half22float2(*(__half2*)&v[j].x);
            float2 f1 = __half22float2(*(__half2*)&v[j].y);
            a0 += f0.x; a1 += f0.y; a2 += f1.x; a3 += f1.y;
        }
        i += 8;
    }
    for (; i < end; i++) {
        int r = csr_src[i];
        uint2 vv = gin2[(size_t)r * 8 + l];
        float2 f0 = __half22float2(*(__half2*)&vv.x);
        float2 f1 = __half22float2(*(__half2*)&vv.y);
        a0 += f0.x; a1 += f0.y; a2 += f1.x; a3 += f1.y;
    }
}

// ---------------- fused mid layer: 8 lanes/node, 32 nodes/block ----------------
__global__ void layer_mid_fused(const uint2* __restrict__ gin2, const int* __restrict__ rowstart,
                                const int* __restrict__ csr_src, const float* __restrict__ dis,
                                const float* __restrict__ W, const float* __restrict__ bb,
                                uint2* __restrict__ gout2, int n, int E) {
    __shared__ float Ws[F * F];
    __shared__ float hs[32][F + 1];
    int tid = threadIdx.x;
    for (int i = tid; i < F * F; i += 256) Ws[i] = W[i];
    int grp = tid >> 3;
    int l = tid & 7;
    int node = blockIdx.x * 32 + grp;
    int start = rowstart[node], end = rowstart[node + 1];
    float a0, a1, a2, a3;
    gather16(gin2, csr_src, start, end, l, a0, a1, a2, a3);
    float dv = dis[node];
    int fb = 4 * l;
    hs[grp][fb]     = dv * a0;
    hs[grp][fb + 1] = dv * a1;
    hs[grp][fb + 2] = dv * a2;
    hs[grp][fb + 3] = dv * a3;
    __syncthreads();
    float acc0 = bb[fb], acc1 = bb[fb+1], acc2 = bb[fb+2], acc3 = bb[fb+3];
#pragma unroll
    for (int k = 0; k < F; k++) {
        float hv = hs[grp][k];
        acc0 += hv * Ws[k*F+fb];
        acc1 += hv * Ws[k*F+fb+1];
        acc2 += hv * Ws[k*F+fb+2];
        acc3 += hv * Ws[k*F+fb+3];
    }
    float h0 = acc0 > 0.0f ? acc0 : 0.0f;
    float h1 = acc1 > 0.0f ? acc1 : 0.0f;
    float h2 = acc2 > 0.0f ? acc2 : 0.0f;
    float h3 = acc3 > 0.0f ? acc3 : 0.0f;
    __half2 o0 = __floats2half2_rn(dv * h0, dv * h1);
    __half2 o1 = __floats2half2_rn(dv * h2, dv * h3);
    uint2 pack;
    pack.x = *(unsigned*)&o0;
    pack.y = *(unsigned*)&o1;
    gout2[(size_t)node * 8 + l] = pack;
}

// ---------------- fused last layer: 8 lanes/node + heads + argmax partials ----------------
__global__ void layer_last_fused(const uint2* __restrict__ gin2, const int* __restrict__ rowstart,
                                 const int* __restrict__ csr_src, const float* __restrict__ dis,
                                 const float* __restrict__ W3, const float* __restrict__ b3,
                                 const float* __restrict__ Wd, const float* __restrict__ bd,
                                 const float* __restrict__ Wa, const float* __restrict__ ba,
                                 float* __restrict__ out, float* __restrict__ pmax,
                                 int* __restrict__ pidx, int n, int E) {
    __shared__ float Ws[F * F];
    __shared__ float hs[32][F + 1];
    __shared__ float gmax[32];
    __shared__ int gidx[32];
    int tid = threadIdx.x;
    for (int i = tid; i < F * F; i += 256) Ws[i] = W3[i];
    int grp = tid >> 3;
    int l = tid & 7;
    int node = blockIdx.x * 32 + grp;
    int start = rowstart[node], end = rowstart[node + 1];
    float a0, a1, a2, a3;
    gather16(gin2, csr_src, start, end, l, a0, a1, a2, a3);
    float dv = dis[node];
    int fb = 4 * l;
    hs[grp][fb]     = dv * a0;
    hs[grp][fb + 1] = dv * a1;
    hs[grp][fb + 2] = dv * a2;
    hs[grp][fb + 3] = dv * a3;
    __syncthreads();
    float acc0 = b3[fb], acc1 = b3[fb+1], acc2 = b3[fb+2], acc3 = b3[fb+3];
#pragma unroll
    for (int k = 0; k < F; k++) {
        float hv = hs[grp][k];
        acc0 += hv * Ws[k*F+fb];
        acc1 += hv * Ws[k*F+fb+1];
        acc2 += hv * Ws[k*F+fb+2];
        acc3 += hv * Ws[k*F+fb+3];
    }
    float h0 = acc0 > 0.0f ? acc0 : 0.0f;
    float h1 = acc1 > 0.0f ? acc1 : 0.0f;
    float h2 = acc2 > 0.0f ? acc2 : 0.0f;
    float h3 = acc3 > 0.0f ? acc3 : 0.0f;
    float dterm = h0 * Wd[fb] + h1 * Wd[fb+1] + h2 * Wd[fb+2] + h3 * Wd[fb+3];
    float aterm = h0 * Wa[fb] + h1 * Wa[fb+1] + h2 * Wa[fb+2] + h3 * Wa[fb+3];
#pragma unroll
    for (int off = 4; off > 0; off >>= 1) {
        dterm += __shfl_xor(dterm, off, 8);
        aterm += __shfl_xor(aterm, off, 8);
    }
    if (l == 0) {
        out[node] = dterm + bd[0];
        float asc = aterm + ba[0];
        out[N_NODES + node] = asc;
        gmax[grp] = asc;
        gidx[grp] = node;
    }
    __syncthreads();
    if (tid == 0) {
        float best = gmax[0]; int bi = gidx[0];
        for (int g = 1; g < 32; g++) {
            if (gmax[g] > best || (gmax[g] == best && gidx[g] < bi)) { best = gmax[g]; bi = gidx[g]; }
        }
        pmax[blockIdx.x] = best;
        pidx[blockIdx.x] = bi;
    }
}

// ---------------- final: argmax, re-gather target row from gd_b (fp16), tail heads ----------------
__global__ void final_kernel(const float* __restrict__ pmax, const int* __restrict__ pidx, int nblocks,
                             const __half* __restrict__ gin, const int* __restrict__ rowstart,
                             const int* __restrict__ csr_src, const float* __restrict__ dis,
                             const float* __restrict__ W3, const float* __restrict__ b3,
                             const float* __restrict__ Wt, const float* __restrict__ bt,
                             const float* __restrict__ Wact, const float* __restrict__ bact,
                             float* __restrict__ out) {
    __shared__ float smax[256];
    __shared__ int sidx[256];
    __shared__ float part[8][F];
    __shared__ float hrow[F];
    __shared__ float ht[F];
    int tid = threadIdx.x;
    float best = -INFINITY; int bi = 0x7fffffff;
    for (int i = tid; i < nblocks; i += 256) {
        float v = pmax[i]; int ix = pidx[i];
        if (v > best || (v == best && ix < bi)) { best = v; bi = ix; }
    }
    smax[tid] = best; sidx[tid] = bi;
    __syncthreads();
    for (int st = 128; st > 0; st >>= 1) {
        if (tid < st) {
            float v2 = smax[tid + st]; int i2 = sidx[tid + st];
            if (v2 > smax[tid] || (v2 == smax[tid] && i2 < sidx[tid])) { smax[tid] = v2; sidx[tid] = i2; }
        }
        __syncthreads();
    }
    int target = sidx[0];
    int g = tid >> 5, f = tid & 31;
    int start = rowstart[target], end = rowstart[target + 1];
    float acc = 0.0f;
    for (int i = start + g; i < end; i += 8)
        acc += __half2float(gin[(size_t)csr_src[i] * F + f]);
    part[g][f] = acc;
    __syncthreads();
    if (tid < F) {
        float s = 0.0f;
#pragma unroll
        for (int gg = 0; gg < 8; gg++) s += part[gg][tid];
        hrow[tid] = dis[target] * s;
    }
    __syncthreads();
    if (tid < F) {
        float a = b3[tid];
#pragma unroll
        for (int k = 0; k < F; k++) a += hrow[k] * W3[k*F+tid];
        ht[tid] = a > 0.0f ? a : 0.0f;
    }
    __syncthreads();
    if (tid < 2) {
        float a = bt[tid];
#pragma unroll
        for (int k = 0; k < F; k++) a += ht[k] * Wt[k*2+tid];
        out[2 * N_NODES + tid] = a;
    } else if (tid < 11) {
        int j = tid - 2;
        float a = bact[j];
#pragma unroll
        for (int k = 0; k < F; k++) a += ht[k] * Wact[k*9+j];
        out[2 * N_NODES + 2 + j] = a;
    }
}

extern "C" void kernel_launch(void* const* d_in, const int* in_sizes, int n_in,
                              void* d_out, int out_size, void* d_ws, size_t ws_size,
                              hipStream_t stream) {
    const float* x  = (const float*)d_in[0];
    const int*   ei = (const int*)d_in[1];
    const int E = in_sizes[1] / 2;
    const int* row = ei;
    const int* col = ei + E;
    const float* W1 = (const float*)d_in[2];
    const float* b1 = (const float*)d_in[3];
    const float* W2 = (const float*)d_in[4];
    const float* b2 = (const float*)d_in[5];
    const float* W3 = (const float*)d_in[6];
    const float* b3 = (const float*)d_in[7];
    const float* Wd = (const float*)d_in[8];
    const float* bd = (const float*)d_in[9];
    const float* Wa = (const float*)d_in[10];
    const float* ba = (const float*)d_in[11];
    const float* Wt = (const float*)d_in[12];
    const float* bt = (const float*)d_in[13];
    const float* Wact = (const float*)d_in[14];
    const float* bact = (const float*)d_in[15];

    float* out = (float*)d_out;
    float* ws  = (float*)d_ws;

    // workspace layout (floats):
    //   dis [0,N) | xd [N,9N) | gd_a (half,16N fl) [17N,33N) | gd_b (half,16N fl) [33N,49N)
    //   ints from 49N: deg[N] | cur[N] | rowstart[N+1] | csr_src[E] |
    //     pmax[12500] | pidx[12500] | blockoff[NSCB+1] | ticket[1]
    float*    dis      = ws;
    float*    xd       = ws + N_NODES;
    __half*   gd_a     = (__half*)(ws + (size_t)17 * N_NODES);
    __half*   gd_b     = (__half*)(ws + (size_t)33 * N_NODES);
    int*      deg      = (int*)(ws + (size_t)49 * N_NODES);       // N
    int*      cur      = deg + N_NODES;                           // N
    int*      rowstart = cur + N_NODES;                           // N+1
    int*      csr_src  = rowstart + N_NODES + 1;                  // E
    float*    pmax     = (float*)(csr_src + E);                   // 3125 used
    int*      pidx     = (int*)(pmax + 12500);                    // 3125 used
    int*      blockoff = pidx + 12500;                            // NSCB+1
    int*      ticket   = blockoff + NSCB + 1;                     // 1

    const int B = 256;
    const int nb32 = (N_NODES + 31) / 32;          // 3125 (exact, no partial block)

    // ---- CSR build: zero -> deg(atomic) -> scanA(ticket) -> scanB -> scatter_direct ----
    zero_kernel<<<NSCB, 1024, 0, stream>>>(deg, ticket);
    deg_kernel<<<2048, B, 0, stream>>>(col, deg, E);
    scanA_kernel<<<NSCB, 1024, 0, stream>>>(deg, blockoff, rowstart, ticket);
    scanB_kernel<<<NSCB, 1024, 0, stream>>>(deg, blockoff, rowstart, cur, dis, x, xd);
    scatter_direct<<<2048, B, 0, stream>>>(row, col, cur, csr_src, E);

    // ---- layer 1 (fused gather + W1 transform) ----
    layer1_fused<<<nb32, B, 0, stream>>>(xd, rowstart, csr_src, dis, W1, b1, gd_a, N_NODES);

    // ---- layer 2 (fused gather + transform, 16-deep pipelined gather) ----
    layer_mid_fused<<<nb32, B, 0, stream>>>((const uint2*)gd_a, rowstart, csr_src, dis,
                                            W2, b2, (uint2*)gd_b, N_NODES, E);

    // ---- layer 3 + heads (fused, 16-deep pipelined gather) ----
    layer_last_fused<<<nb32, B, 0, stream>>>((const uint2*)gd_b, rowstart, csr_src, dis,
                                             W3, b3, Wd, bd, Wa, ba, out, pmax, pidx, N_NODES, E);
    final_kernel<<<1, B, 0, stream>>>(pmax, pidx, nb32, gd_b, rowstart, csr_src, dis,
                                      W3, b3, Wt, bt, Wact, bact, out);
}

// Round 10
// 221.010 us; speedup vs baseline: 1.7858x; 1.7858x over previous
//
#include <hip/hip_runtime.h>
#include <hip/hip_fp16.h>
#include <math.h>

// R27 = exact restore of R25 (measured 227.5us, session best).
// R26's global-atomic CSR build refuted both atomic hypotheses:
//   scatter_direct 120us (WRITE_SIZE 107MB = E x 64B line-granularity writes),
//   deg_kernel cross-XCD atomic ping-pong (~100us residual).
// The inherited zero-device-atomic bucket design is load-bearing. Ledger:
// R18 228.9 | R19 235.4 | R20 280.5 | R21 228.1 | R22 757.5 | R23 244.8 |
// R24b 424.0 | R25 227.5 | R26 394.7.

#define N_NODES 100000
#define F 32
#define BUCKET 64
#define NB ((N_NODES + BUCKET - 1) / BUCKET)   // 1563
#define NBLK 256                                // chunks for hist/scatter passes
#define SMAX 1536                               // per-bucket sort capacity
#define TBKT 32                                 // buckets per scan block
#define NGRP 8                                  // 256 thr / 32 lanes
#define RPG (NBLK / NGRP)                       // 32 rows (chunks) per group

// ---------------- pass 1: per-chunk bucket histogram (LDS, 1024 thr) ----------------
__global__ void hist_kernel(const int* __restrict__ col, int* __restrict__ counts, int E,
                            int* __restrict__ ticket) {
    __shared__ int hist[NB];
    int tid = threadIdx.x, blk = blockIdx.x;
    if (blk == 0 && tid == 0) *ticket = 0;       // re-arm decoupled scan each replay
    for (int i = tid; i < NB; i += 1024) hist[i] = 0;
    __syncthreads();
    int chunk = (((E + NBLK - 1) / NBLK) + 1) & ~1;    // even -> int2 alignment
    int beg = blk * chunk;
    int end = beg + chunk; if (end > E) end = E;
    int cnt = end - beg; if (cnt < 0) cnt = 0;
    int pairs = cnt >> 1;
    const int2* c2 = (const int2*)(col + beg);
    for (int p = tid; p < pairs; p += 1024) {
        int2 v = c2[p];
        atomicAdd(&hist[v.x >> 6], 1);
        atomicAdd(&hist[v.y >> 6], 1);
    }
    if ((cnt & 1) && tid == 0) atomicAdd(&hist[col[end - 1] >> 6], 1);
    __syncthreads();
    for (int i = tid; i < NB; i += 1024) counts[(size_t)blk * NB + i] = hist[i];
}

// ---------------- pass 2: coalesced tiled segmented scan + last-block global scan ----------------
__global__ void scan_kernel(int* __restrict__ counts, int* __restrict__ tot,
                            int* __restrict__ bucket_base, int* __restrict__ rowstart,
                            int* __restrict__ ticket) {
    __shared__ int tile[NBLK][TBKT];     // 32 KB: exclusive local prefixes
    __shared__ int wtot[NGRP][TBKT];
    int tid = threadIdx.x;
    int g = tid >> 5, bl = tid & 31;
    int b = blockIdx.x * TBKT + bl;
    bool valid = (b < NB);
    int jbase = g * RPG;
    int run = 0;
#pragma unroll
    for (int r = 0; r < RPG; r++) {
        int j = jbase + r;
        int v = valid ? counts[(size_t)j * NB + b] : 0;
        tile[j][bl] = run;
        run += v;
    }
    wtot[g][bl] = run;
    __syncthreads();
    int off = 0;
#pragma unroll
    for (int gg = 0; gg < NGRP; gg++) {
        int w = wtot[gg][bl];
        if (gg < g) off += w;
    }
    if (valid) {
#pragma unroll
        for (int r = 0; r < RPG; r++) {
            int j = jbase + r;
            counts[(size_t)j * NB + b] = tile[j][bl] + off;
        }
        if (g == NGRP - 1) tot[b] = off + run;   // bucket total
    }
    // ---- decoupled last-block global scan of tot -> bucket_base (49 blocks: cheap) ----
    __shared__ int lastflag;
    __threadfence();
    __syncthreads();
    if (tid == 0) lastflag = (atomicAdd(ticket, 1) == (int)gridDim.x - 1);
    __syncthreads();
    if (!lastflag) return;
    __threadfence();
    constexpr int PER = (NB + 255) / 256;              // 7
    __shared__ int bsum[256];
    int base = tid * PER;
    int loc[PER];
    int s = 0;
#pragma unroll
    for (int k = 0; k < PER; k++) {
        int idx = base + k;
        int v = (idx < NB) ? tot[idx] : 0;
        loc[k] = s;
        s += v;
    }
    bsum[tid] = s;
    __syncthreads();
    for (int off2 = 1; off2 < 256; off2 <<= 1) {
        int v = (tid >= off2) ? bsum[tid - off2] : 0;
        __syncthreads();
        bsum[tid] += v;
        __syncthreads();
    }
    int excl = bsum[tid] - s;
#pragma unroll
    for (int k = 0; k < PER; k++) {
        int idx = base + k;
        if (idx < NB) bucket_base[idx] = excl + loc[k];
    }
    if (tid == 255) {
        bucket_base[NB] = bsum[255];
        rowstart[N_NODES] = bsum[255];
    }
}

// ---------------- pass 3: scatter into bucket-grouped storage (LDS cursors, 1024 thr) ----------------
__global__ void scatter_kernel(const int* __restrict__ row, const int* __restrict__ col,
                               const int* __restrict__ counts, const int* __restrict__ bucket_base,
                               unsigned* __restrict__ storage, int E) {
    __shared__ int cur[NB];
    int tid = threadIdx.x, blk = blockIdx.x;
    for (int i = tid; i < NB; i += 1024)
        cur[i] = counts[(size_t)blk * NB + i] + bucket_base[i];
    __syncthreads();
    int chunk = (((E + NBLK - 1) / NBLK) + 1) & ~1;    // must match hist_kernel
    int beg = blk * chunk;
    int end = beg + chunk; if (end > E) end = E;
    int cnt = end - beg; if (cnt < 0) cnt = 0;
    int pairs = cnt >> 1;
    const int2* c2 = (const int2*)(col + beg);
    const int2* r2 = (const int2*)(row + beg);
    for (int p = tid; p < pairs; p += 1024) {
        int2 c = c2[p];
        int2 r = r2[p];
        int pos0 = atomicAdd(&cur[c.x >> 6], 1);        // LDS atomic, block-owned segment
        storage[pos0] = ((unsigned)(c.x & 63) << 17) | (unsigned)r.x;
        int pos1 = atomicAdd(&cur[c.y >> 6], 1);
        storage[pos1] = ((unsigned)(c.y & 63) << 17) | (unsigned)r.y;
    }
    if ((cnt & 1) && tid == 0) {
        int c = col[end - 1], r = row[end - 1];
        int pos = atomicAdd(&cur[c >> 6], 1);
        storage[pos] = ((unsigned)(c & 63) << 17) | (unsigned)r;
    }
}

// ---------------- per-bucket LDS counting sort -> CSR + dis + xd ----------------
__global__ void csr_build_kernel(const unsigned* __restrict__ storage, const int* __restrict__ bucket_base,
                                 int* __restrict__ rowstart, int* __restrict__ csr_src,
                                 float* __restrict__ dis, const float* __restrict__ x,
                                 float* __restrict__ xd, int n) {
    __shared__ unsigned sh[SMAX];
    __shared__ int outloc[SMAX];
    __shared__ int hist[BUCKET];
    __shared__ int pre[BUCKET];
    __shared__ int cur[BUCKET];
    __shared__ float dloc[BUCKET];
    int b = blockIdx.x, tid = threadIdx.x;
    if (tid < BUCKET) hist[tid] = 0;
    __syncthreads();
    int base = bucket_base[b];
    int tot = bucket_base[b + 1] - base;
    if (tot > SMAX) tot = SMAX;
    for (int i = tid; i < tot; i += 256) sh[i] = storage[base + i];
    __syncthreads();
    for (int i = tid; i < tot; i += 256) atomicAdd(&hist[sh[i] >> 17], 1);
    __syncthreads();
    if (tid < BUCKET) pre[tid] = hist[tid];
    __syncthreads();
    for (int off = 1; off < BUCKET; off <<= 1) {
        int v = 0;
        if (tid < BUCKET && tid >= off) v = pre[tid - off];
        __syncthreads();
        if (tid < BUCKET && tid >= off) pre[tid] += v;
        __syncthreads();
    }
    if (tid < BUCKET) {
        int excl = pre[tid] - hist[tid];
        cur[tid] = excl;
        int node = b * BUCKET + tid;
        if (node < n) {
            rowstart[node] = base + excl;
            int d = hist[tid];
            float dv = (d > 0) ? rsqrtf((float)d) : 0.0f;
            dis[node] = dv;
            dloc[tid] = dv;
        }
    }
    __syncthreads();
    for (int i = tid; i < BUCKET * 8; i += 256) {
        int nl = i >> 3, f = i & 7;
        int node = b * BUCKET + nl;
        if (node < n) xd[(size_t)node * 8 + f] = (f < 5) ? dloc[nl] * x[(size_t)node * 5 + f] : 0.0f;
    }
    for (int i = tid; i < tot; i += 256) {
        unsigned p = sh[i];
        int pos = atomicAdd(&cur[p >> 17], 1);
        outloc[pos] = (int)(p & 0x1FFFF);
    }
    __syncthreads();
    for (int i = tid; i < tot; i += 256) csr_src[base + i] = outloc[i];
}

// ---------------- layer 1 fused: gather xd (8 lanes/node) + W1 transform -> gd_a fp16 ----------------
__global__ void layer1_fused(const float* __restrict__ xd, const int* __restrict__ rowstart,
                             const int* __restrict__ csr_src, const float* __restrict__ dis,
                             const float* __restrict__ W1, const float* __restrict__ b1,
                             __half* __restrict__ gda, int n) {
    __shared__ float Ws[5 * F];
    __shared__ float s1s[32][8];
    int tid = threadIdx.x;
    if (tid < 5 * F) Ws[tid] = W1[tid];
    int grp = tid >> 3, f = tid & 7;
    int node = blockIdx.x * 32 + grp;
    float sum = 0.0f;
    if (node < n) {
        int start = rowstart[node], end = rowstart[node + 1];
        float a0 = 0, a1 = 0, a2 = 0, a3 = 0, a4 = 0, a5 = 0, a6 = 0, a7 = 0;
        int i = start;
        for (; i + 7 < end; i += 8) {
            int r0 = csr_src[i], r1 = csr_src[i+1], r2 = csr_src[i+2], r3 = csr_src[i+3];
            int r4 = csr_src[i+4], r5 = csr_src[i+5], r6 = csr_src[i+6], r7 = csr_src[i+7];
            a0 += xd[r0*8+f]; a1 += xd[r1*8+f]; a2 += xd[r2*8+f]; a3 += xd[r3*8+f];
            a4 += xd[r4*8+f]; a5 += xd[r5*8+f]; a6 += xd[r6*8+f]; a7 += xd[r7*8+f];
        }
        for (; i < end; i++) a0 += xd[csr_src[i]*8+f];
        sum = ((a0+a1)+(a2+a3)) + ((a4+a5)+(a6+a7));
    }
    s1s[grp][f] = sum;
    __syncthreads();
    if (node < n) {
        float dv = dis[node];
        float sk0 = dv * s1s[grp][0], sk1 = dv * s1s[grp][1], sk2 = dv * s1s[grp][2];
        float sk3 = dv * s1s[grp][3], sk4 = dv * s1s[grp][4];
        int fb = f * 4;
#pragma unroll
        for (int j = 0; j < 4; j++) {
            int ff = fb + j;
            float acc = b1[ff] + sk0 * Ws[0*F+ff] + sk1 * Ws[1*F+ff] + sk2 * Ws[2*F+ff]
                       + sk3 * Ws[3*F+ff] + sk4 * Ws[4*F+ff];
            float h = acc > 0.0f ? acc : 0.0f;
            gda[(size_t)node * F + ff] = __float2half(dv * h);
        }
    }
}

// ======== 16-deep 8-lane gather: 16 edges in flight, next-16 indices prefetched ========
__device__ __forceinline__ void gather16(const uint2* __restrict__ gin2,
                                         const int* __restrict__ csr_src,
                                         int start, int end, int l,
                                         float& a0, float& a1, float& a2, float& a3) {
    a0 = a1 = a2 = a3 = 0.0f;
    int i = start;
    if (i + 16 <= end) {
        int i0 = csr_src[i + l];
        int i1 = csr_src[i + 8 + l];
        while (i + 16 <= end) {
            int nexti = i + 16;
            int n0 = 0, n1 = 0;
            if (nexti + 16 <= end) {
                n0 = csr_src[nexti + l];
                n1 = csr_src[nexti + 8 + l];
            }
            uint2 v[16];
#pragma unroll
            for (int j = 0; j < 8; j++) {
                int r = __shfl(i0, j, 8);
                v[j] = gin2[(size_t)r * 8 + l];
            }
#pragma unroll
            for (int j = 0; j < 8; j++) {
                int r = __shfl(i1, j, 8);
                v[8 + j] = gin2[(size_t)r * 8 + l];
            }
#pragma unroll
            for (int j = 0; j < 16; j++) {
                float2 f0 = __half22float2(*(__half2*)&v[j].x);
                float2 f1 = __half22float2(*(__half2*)&v[j].y);
                a0 += f0.x; a1 += f0.y; a2 += f1.x; a3 += f1.y;
            }
            i0 = n0; i1 = n1;
            i = nexti;
        }
    }
    if (i + 8 <= end) {
        int idx = csr_src[i + l];
        uint2 v[8];
#pragma unroll
        for (int j = 0; j < 8; j++) {
            int r = __shfl(idx, j, 8);
            v[j] = gin2[(size_t)r * 8 + l];
        }
#pragma unroll
        for (int j = 0; j < 8; j++) {
            float2 f0 = __half22float2(*(__half2*)&v[j].x);
            float2 f1 = __half22float2(*(__half2*)&v[j].y);
            a0 += f0.x; a1 += f0.y; a2 += f1.x; a3 += f1.y;
        }
        i += 8;
    }
    for (; i < end; i++) {
        int r = csr_src[i];
        uint2 vv = gin2[(size_t)r * 8 + l];
        float2 f0 = __half22float2(*(__half2*)&vv.x);
        float2 f1 = __half22float2(*(__half2*)&vv.y);
        a0 += f0.x; a1 += f0.y; a2 += f1.x; a3 += f1.y;
    }
}

// ---------------- fused mid layer: 8 lanes/node, 32 nodes/block ----------------
__global__ void layer_mid_fused(const uint2* __restrict__ gin2, const int* __restrict__ rowstart,
                                const int* __restrict__ csr_src, const float* __restrict__ dis,
                                const float* __restrict__ W, const float* __restrict__ bb,
                                uint2* __restrict__ gout2, int n, int E) {
    __shared__ float Ws[F * F];
    __shared__ float hs[32][F + 1];
    int tid = threadIdx.x;
    for (int i = tid; i < F * F; i += 256) Ws[i] = W[i];
    int grp = tid >> 3;
    int l = tid & 7;
    int node = blockIdx.x * 32 + grp;          // n = 100000 = 3125*32, no partial blocks
    int start = rowstart[node], end = rowstart[node + 1];
    float a0, a1, a2, a3;
    gather16(gin2, csr_src, start, end, l, a0, a1, a2, a3);
    float dv = dis[node];
    int fb = 4 * l;
    hs[grp][fb]     = dv * a0;
    hs[grp][fb + 1] = dv * a1;
    hs[grp][fb + 2] = dv * a2;
    hs[grp][fb + 3] = dv * a3;
    __syncthreads();
    float acc0 = bb[fb], acc1 = bb[fb+1], acc2 = bb[fb+2], acc3 = bb[fb+3];
#pragma unroll
    for (int k = 0; k < F; k++) {
        float hv = hs[grp][k];
        acc0 += hv * Ws[k*F+fb];
        acc1 += hv * Ws[k*F+fb+1];
        acc2 += hv * Ws[k*F+fb+2];
        acc3 += hv * Ws[k*F+fb+3];
    }
    float h0 = acc0 > 0.0f ? acc0 : 0.0f;
    float h1 = acc1 > 0.0f ? acc1 : 0.0f;
    float h2 = acc2 > 0.0f ? acc2 : 0.0f;
    float h3 = acc3 > 0.0f ? acc3 : 0.0f;
    __half2 o0 = __floats2half2_rn(dv * h0, dv * h1);
    __half2 o1 = __floats2half2_rn(dv * h2, dv * h3);
    uint2 pack;
    pack.x = *(unsigned*)&o0;
    pack.y = *(unsigned*)&o1;
    gout2[(size_t)node * 8 + l] = pack;
}

// ---------------- fused last layer: 8 lanes/node + heads + argmax partials ----------------
__global__ void layer_last_fused(const uint2* __restrict__ gin2, const int* __restrict__ rowstart,
                                 const int* __restrict__ csr_src, const float* __restrict__ dis,
                                 const float* __restrict__ W3, const float* __restrict__ b3,
                                 const float* __restrict__ Wd, const float* __restrict__ bd,
                                 const float* __restrict__ Wa, const float* __restrict__ ba,
                                 float* __restrict__ out, float* __restrict__ pmax,
                                 int* __restrict__ pidx, int n, int E) {
    __shared__ float Ws[F * F];
    __shared__ float hs[32][F + 1];
    __shared__ float gmax[32];
    __shared__ int gidx[32];
    int tid = threadIdx.x;
    for (int i = tid; i < F * F; i += 256) Ws[i] = W3[i];
    int grp = tid >> 3;
    int l = tid & 7;
    int node = blockIdx.x * 32 + grp;
    int start = rowstart[node], end = rowstart[node + 1];
    float a0, a1, a2, a3;
    gather16(gin2, csr_src, start, end, l, a0, a1, a2, a3);
    float dv = dis[node];
    int fb = 4 * l;
    hs[grp][fb]     = dv * a0;
    hs[grp][fb + 1] = dv * a1;
    hs[grp][fb + 2] = dv * a2;
    hs[grp][fb + 3] = dv * a3;
    __syncthreads();
    float acc0 = b3[fb], acc1 = b3[fb+1], acc2 = b3[fb+2], acc3 = b3[fb+3];
#pragma unroll
    for (int k = 0; k < F; k++) {
        float hv = hs[grp][k];
        acc0 += hv * Ws[k*F+fb];
        acc1 += hv * Ws[k*F+fb+1];
        acc2 += hv * Ws[k*F+fb+2];
        acc3 += hv * Ws[k*F+fb+3];
    }
    float h0 = acc0 > 0.0f ? acc0 : 0.0f;
    float h1 = acc1 > 0.0f ? acc1 : 0.0f;
    float h2 = acc2 > 0.0f ? acc2 : 0.0f;
    float h3 = acc3 > 0.0f ? acc3 : 0.0f;
    float dterm = h0 * Wd[fb] + h1 * Wd[fb+1] + h2 * Wd[fb+2] + h3 * Wd[fb+3];
    float aterm = h0 * Wa[fb] + h1 * Wa[fb+1] + h2 * Wa[fb+2] + h3 * Wa[fb+3];
#pragma unroll
    for (int off = 4; off > 0; off >>= 1) {
        dterm += __shfl_xor(dterm, off, 8);
        aterm += __shfl_xor(aterm, off, 8);
    }
    if (l == 0) {
        out[node] = dterm + bd[0];
        float asc = aterm + ba[0];
        out[N_NODES + node] = asc;
        gmax[grp] = asc;
        gidx[grp] = node;
    }
    __syncthreads();
    if (tid == 0) {
        float best = gmax[0]; int bi = gidx[0];
        for (int g = 1; g < 32; g++) {
            if (gmax[g] > best || (gmax[g] == best && gidx[g] < bi)) { best = gmax[g]; bi = gidx[g]; }
        }
        pmax[blockIdx.x] = best;
        pidx[blockIdx.x] = bi;
    }
}

// ---------------- final: argmax, re-gather target row from gd_b (fp16), tail heads ----------------
__global__ void final_kernel(const float* __restrict__ pmax, const int* __restrict__ pidx, int nblocks,
                             const __half* __restrict__ gin, const int* __restrict__ rowstart,
                             const int* __restrict__ csr_src, const float* __restrict__ dis,
                             const float* __restrict__ W3, const float* __restrict__ b3,
                             const float* __restrict__ Wt, const float* __restrict__ bt,
                             const float* __restrict__ Wact, const float* __restrict__ bact,
                             float* __restrict__ out) {
    __shared__ float smax[256];
    __shared__ int sidx[256];
    __shared__ float part[8][F];
    __shared__ float hrow[F];
    __shared__ float ht[F];
    int tid = threadIdx.x;
    float best = -INFINITY; int bi = 0x7fffffff;
    for (int i = tid; i < nblocks; i += 256) {
        float v = pmax[i]; int ix = pidx[i];
        if (v > best || (v == best && ix < bi)) { best = v; bi = ix; }
    }
    smax[tid] = best; sidx[tid] = bi;
    __syncthreads();
    for (int st = 128; st > 0; st >>= 1) {
        if (tid < st) {
            float v2 = smax[tid + st]; int i2 = sidx[tid + st];
            if (v2 > smax[tid] || (v2 == smax[tid] && i2 < sidx[tid])) { smax[tid] = v2; sidx[tid] = i2; }
        }
        __syncthreads();
    }
    int target = sidx[0];
    int g = tid >> 5, f = tid & 31;
    int start = rowstart[target], end = rowstart[target + 1];
    float acc = 0.0f;
    for (int i = start + g; i < end; i += 8)
        acc += __half2float(gin[(size_t)csr_src[i] * F + f]);
    part[g][f] = acc;
    __syncthreads();
    if (tid < F) {
        float s = 0.0f;
#pragma unroll
        for (int gg = 0; gg < 8; gg++) s += part[gg][tid];
        hrow[tid] = dis[target] * s;
    }
    __syncthreads();
    if (tid < F) {
        float a = b3[tid];
#pragma unroll
        for (int k = 0; k < F; k++) a += hrow[k] * W3[k*F+tid];
        ht[tid] = a > 0.0f ? a : 0.0f;
    }
    __syncthreads();
    if (tid < 2) {
        float a = bt[tid];
#pragma unroll
        for (int k = 0; k < F; k++) a += ht[k] * Wt[k*2+tid];
        out[2 * N_NODES + tid] = a;
    } else if (tid < 11) {
        int j = tid - 2;
        float a = bact[j];
#pragma unroll
        for (int k = 0; k < F; k++) a += ht[k] * Wact[k*9+j];
        out[2 * N_NODES + 2 + j] = a;
    }
}

extern "C" void kernel_launch(void* const* d_in, const int* in_sizes, int n_in,
                              void* d_out, int out_size, void* d_ws, size_t ws_size,
                              hipStream_t stream) {
    const float* x  = (const float*)d_in[0];
    const int*   ei = (const int*)d_in[1];
    const int E = in_sizes[1] / 2;
    const int* row = ei;
    const int* col = ei + E;
    const float* W1 = (const float*)d_in[2];
    const float* b1 = (const float*)d_in[3];
    const float* W2 = (const float*)d_in[4];
    const float* b2 = (const float*)d_in[5];
    const float* W3 = (const float*)d_in[6];
    const float* b3 = (const float*)d_in[7];
    const float* Wd = (const float*)d_in[8];
    const float* bd = (const float*)d_in[9];
    const float* Wa = (const float*)d_in[10];
    const float* ba = (const float*)d_in[11];
    const float* Wt = (const float*)d_in[12];
    const float* bt = (const float*)d_in[13];
    const float* Wact = (const float*)d_in[14];
    const float* bact = (const float*)d_in[15];

    float* out = (float*)d_out;
    float* ws  = (float*)d_ws;

    // workspace layout (floats):
    //   dis [0,N) | xd [N,9N) | gd_a (half,16N fl) [17N,33N) | gd_b (half,16N fl) [33N,49N)
    //   storage (E u32 <= 16N slots, exact) aliases gd_b; dead before layer_mid writes gd_b
    //   ints from 49N: bucket_base[NB+1] | counts[NBLK*NB] |
    //     rowstart[N+1] | csr_src[E] | pmax[12500] | pidx[12500] | tot[NB] | ticket[1]
    float*    dis      = ws;
    float*    xd       = ws + N_NODES;
    __half*   gd_a     = (__half*)(ws + (size_t)17 * N_NODES);
    __half*   gd_b     = (__half*)(ws + (size_t)33 * N_NODES);
    unsigned* storage  = (unsigned*)(ws + (size_t)33 * N_NODES);
    int*      bucket_base = (int*)(ws + (size_t)49 * N_NODES);    // NB+1
    int*      counts   = bucket_base + NB + 1;                    // NBLK*NB = 400128
    int*      rowstart = counts + NBLK * NB;                      // N+1
    int*      csr_src  = rowstart + N_NODES + 1;                  // E
    float*    pmax     = (float*)(csr_src + E);                   // 3125 used
    int*      pidx     = (int*)(pmax + 12500);                    // 3125 used
    int*      tot      = pidx + 12500;                            // NB
    int*      ticket   = tot + NB;                                // 1

    const int B = 256;
    const int nb32 = (N_NODES + 31) / 32;          // 3125 (exact, no partial block)
    const int nscan = (NB + TBKT - 1) / TBKT;      // 49

    // ---- CSR build: hist -> coalesced tiled scan (+decoupled global scan) -> scatter -> sort ----
    hist_kernel<<<NBLK, 1024, 0, stream>>>(col, counts, E, ticket);
    scan_kernel<<<nscan, B, 0, stream>>>(counts, tot, bucket_base, rowstart, ticket);
    scatter_kernel<<<NBLK, 1024, 0, stream>>>(row, col, counts, bucket_base, storage, E);
    csr_build_kernel<<<NB, B, 0, stream>>>(storage, bucket_base, rowstart, csr_src, dis, x, xd, N_NODES);

    // ---- layer 1 (fused gather + W1 transform) ----
    layer1_fused<<<nb32, B, 0, stream>>>(xd, rowstart, csr_src, dis, W1, b1, gd_a, N_NODES);

    // ---- layer 2 (fused gather + transform, 16-deep pipelined gather) ----
    layer_mid_fused<<<nb32, B, 0, stream>>>((const uint2*)gd_a, rowstart, csr_src, dis,
                                            W2, b2, (uint2*)gd_b, N_NODES, E);

    // ---- layer 3 + heads (fused, 16-deep pipelined gather) ----
    layer_last_fused<<<nb32, B, 0, stream>>>((const uint2*)gd_b, rowstart, csr_src, dis,
                                             W3, b3, Wd, bd, Wa, ba, out, pmax, pidx, N_NODES, E);
    final_kernel<<<1, B, 0, stream>>>(pmax, pidx, nb32, gd_b, rowstart, csr_src, dis,
                                      W3, b3, Wt, bt, Wact, bact, out);
}